// Round 3
// baseline (10470.182 us; speedup 1.0000x reference)
//
#include <hip/hip_runtime.h>

// Problem constants (fixed by the reference)
#define M_ROWS 106496   // 4096*26  (n,v) rows
#define NBATCH 4096
#define VN 26
#define KNUM 3
#define TS 25

typedef unsigned short u16;
typedef __attribute__((ext_vector_type(8))) short v8s;
typedef __attribute__((ext_vector_type(4))) float v4f;

#define MFMA(a, b, c) __builtin_amdgcn_mfma_f32_16x16x32_bf16(a, b, c, 0, 0, 0)

__device__ __forceinline__ u16 f2bf(float f) {
    unsigned u = __float_as_uint(f);
    u += 0x7FFF + ((u >> 16) & 1);   // RNE
    return (u16)(u >> 16);
}
__device__ __forceinline__ float bf2f(u16 h) {
    return __uint_as_float(((unsigned)h) << 16);
}
__device__ __forceinline__ float sigm(float x) {
    return 1.f / (1.f + __expf(-x));
}
__device__ __forceinline__ float tanh_fast(float x) {
    return 2.f / (1.f + __expf(-2.f * x)) - 1.f;
}

// ---------------------------------------------------------------------------
// mix3: z_k[(n,w),c] = sum_v aadj[k,v,w] * h[(n,v),c], k=0..2.
// z layout: [(n,w)][k*256+c], row stride 768. One block per n.
// ---------------------------------------------------------------------------
__global__ __launch_bounds__(256) void mix3(
    const u16* __restrict__ h, const float* __restrict__ aadj,
    u16* __restrict__ z)
{
    __shared__ u16 hl[VN * 256];
    const int n = blockIdx.x, tid = threadIdx.x;
    const uint4* src = (const uint4*)(h + (size_t)n * VN * 256);
    for (int idx = tid; idx < VN * 256 / 8; idx += 256)
        ((uint4*)hl)[idx] = src[idx];
    __syncthreads();
    float hv[VN];
#pragma unroll
    for (int v = 0; v < VN; ++v) hv[v] = bf2f(hl[v * 256 + tid]);
    size_t zbase = (size_t)n * VN * 768 + tid;
    for (int w = 0; w < VN; ++w) {
        float a0 = 0.f, a1 = 0.f, a2 = 0.f;
#pragma unroll
        for (int v = 0; v < VN; ++v) {
            a0 += hv[v] * aadj[(0 * VN + v) * VN + w];
            a1 += hv[v] * aadj[(1 * VN + v) * VN + w];
            a2 += hv[v] * aadj[(2 * VN + v) * VN + w];
        }
        size_t zr = zbase + (size_t)w * 768;
        z[zr] = f2bf(a0); z[zr + 256] = f2bf(a1); z[zr + 512] = f2bf(a2);
    }
}

// ---------------------------------------------------------------------------
// LDS-free fused GRU. KT K-tiles of 32; tiles 0..KT-2 from Amain (stride SA),
// last tile from xpad[M,32] (x-proj + bias fold). B = wB [768, SB] row-major.
// n-gate x-part via wxn in the peeled last tile (must stay outside r*(...)).
// GB: add per-(w,gate) conv-bias table in epilogue (s<10 folded-conv variant).
// Block: 128 rows x 64 cols x 3 gates; waves 2x2 (64r x 32c each). No LDS in
// the K-loop; no barriers -> compiler emits fine-grained vmcnt pipelining.
// Grid 1-D 3328; decode bx=bid%832 so same-row col-blocks land on one XCD.
// ---------------------------------------------------------------------------
template <int KT, int SA, int SB, int GB>
__global__ __launch_bounds__(256, 3) void gru_direct(
    const u16* __restrict__ Amain, const u16* __restrict__ xpad,
    const u16* __restrict__ hprev, u16* __restrict__ hout,
    const u16* __restrict__ wB, const u16* __restrict__ wxn,
    const float* __restrict__ gbias)
{
    __shared__ float gbl[3 * 26 * 64];
    const int bid = blockIdx.x;
    const int bx = bid % 832, by = bid / 832;
    const int m0 = bx * 128, n0 = by * 64;
    const int tid = threadIdx.x, wid = tid >> 6, lane = tid & 63;
    const int ln = lane & 15, q = lane >> 4;
    const int wm = (wid >> 1) * 64, wn = (wid & 1) * 32;

    if (GB) {
        for (int idx = tid; idx < 4992; idx += 256) {
            int g = idx / 1664, r1 = idx % 1664;
            gbl[idx] = gbias[(size_t)g * 26 * 256 + (r1 / 64) * 256 + n0 + (r1 % 64)];
        }
        __syncthreads();
    }

    const u16* Arow[4];
    const u16* Brow[3][2];
#pragma unroll
    for (int i = 0; i < 4; ++i)
        Arow[i] = Amain + (size_t)(m0 + wm + i * 16 + ln) * SA + q * 8;
#pragma unroll
    for (int g = 0; g < 3; ++g)
#pragma unroll
        for (int j = 0; j < 2; ++j)
            Brow[g][j] = wB + (size_t)(g * 256 + n0 + wn + j * 16 + ln) * SB + q * 8;

    v4f accr[4][2] = {}, accz[4][2] = {}, acch[4][2] = {};

    for (int kt = 0; kt < KT - 1; ++kt) {
        v8s af[4], bf_[3][2];
#pragma unroll
        for (int i = 0; i < 4; ++i) af[i] = *(const v8s*)(Arow[i] + kt * 32);
#pragma unroll
        for (int g = 0; g < 3; ++g)
#pragma unroll
            for (int j = 0; j < 2; ++j)
                bf_[g][j] = *(const v8s*)(Brow[g][j] + kt * 32);
#pragma unroll
        for (int i = 0; i < 4; ++i)
#pragma unroll
            for (int j = 0; j < 2; ++j) {
                accr[i][j] = MFMA(af[i], bf_[0][j], accr[i][j]);
                accz[i][j] = MFMA(af[i], bf_[1][j], accz[i][j]);
                acch[i][j] = MFMA(af[i], bf_[2][j], acch[i][j]);
            }
    }

    // peeled last tile: A = xpad, B = fold cols, + wxn for the n-gate x-part
    v4f accn[4][2] = {};
    {
        v8s af[4], bf_[3][2], bn[2];
#pragma unroll
        for (int i = 0; i < 4; ++i)
            af[i] = *(const v8s*)&xpad[(size_t)(m0 + wm + i * 16 + ln) * 32 + q * 8];
#pragma unroll
        for (int g = 0; g < 3; ++g)
#pragma unroll
            for (int j = 0; j < 2; ++j)
                bf_[g][j] = *(const v8s*)(Brow[g][j] + (KT - 1) * 32);
#pragma unroll
        for (int j = 0; j < 2; ++j)
            bn[j] = *(const v8s*)&wxn[(size_t)(n0 + wn + j * 16 + ln) * 32 + q * 8];
#pragma unroll
        for (int i = 0; i < 4; ++i)
#pragma unroll
            for (int j = 0; j < 2; ++j) {
                accr[i][j] = MFMA(af[i], bf_[0][j], accr[i][j]);
                accz[i][j] = MFMA(af[i], bf_[1][j], accz[i][j]);
                acch[i][j] = MFMA(af[i], bf_[2][j], acch[i][j]);
                accn[i][j] = MFMA(af[i], bn[j], accn[i][j]);
            }
    }

#pragma unroll
    for (int i = 0; i < 4; ++i)
#pragma unroll
        for (int j = 0; j < 2; ++j) {
            int cl = wn + j * 16 + ln, gc = n0 + cl;
#pragma unroll
            for (int r = 0; r < 4; ++r) {
                int gr = m0 + wm + i * 16 + q * 4 + r;
                float ar = accr[i][j][r], az = accz[i][j][r], ah = acch[i][j][r];
                if (GB) {
                    int w = gr % 26;
                    ar += gbl[w * 64 + cl];
                    az += gbl[1664 + w * 64 + cl];
                    ah += gbl[3328 + w * 64 + cl];
                }
                float rg = sigm(ar), zg = sigm(az);
                float nn = tanh_fast(accn[i][j][r] + rg * ah);
                float hp = bf2f(hprev[(size_t)gr * 256 + gc]);
                hout[(size_t)gr * 256 + gc] = f2bf((1.f - zg) * nn + zg * hp);
            }
        }
}

// ---------------------------------------------------------------------------
// Fused MLP + head: hd=lrelu(h@W1^T+b1); hd2=lrelu(hd@W2^T+b2);
// res=hd2@W3^T+b3; pred=P1+res -> out[:,s], pnew, next xpad.
// Block = 64 rows; 4 waves, each owns 64 cols in stages 1&2. hd/hd2 round-trip
// through LDS only. W1/W2 read direct from global (L2-resident).
// ---------------------------------------------------------------------------
__global__ __launch_bounds__(256, 3) void mlp_head(
    const u16* __restrict__ h, const u16* __restrict__ w1,
    const float* __restrict__ b1, const u16* __restrict__ w2,
    const float* __restrict__ b2, const float* __restrict__ w3,
    const float* __restrict__ b3, const float* __restrict__ p1,
    const float* __restrict__ p2, float* __restrict__ pnew,
    u16* __restrict__ xpad, float* __restrict__ out, int s)
{
    __shared__ u16 hdl[64 * 264];
    __shared__ float w3l[768];
    const int tid = threadIdx.x, wid = tid >> 6, lane = tid & 63;
    const int ln = lane & 15, q = lane >> 4;
    const int r0 = blockIdx.x * 64;
    for (int idx = tid; idx < 768; idx += 256) w3l[idx] = w3[idx];

    // stage 1: hd = lrelu(h @ W1^T + b1)
    {
        v4f acc[4][4] = {};
        for (int kt = 0; kt < 8; ++kt) {
            v8s af[4], bf_[4];
#pragma unroll
            for (int i = 0; i < 4; ++i)
                af[i] = *(const v8s*)&h[(size_t)(r0 + i * 16 + ln) * 256 + kt * 32 + q * 8];
#pragma unroll
            for (int j = 0; j < 4; ++j)
                bf_[j] = *(const v8s*)&w1[(size_t)(wid * 64 + j * 16 + ln) * 256 + kt * 32 + q * 8];
#pragma unroll
            for (int i = 0; i < 4; ++i)
#pragma unroll
                for (int j = 0; j < 4; ++j)
                    acc[i][j] = MFMA(af[i], bf_[j], acc[i][j]);
        }
#pragma unroll
        for (int i = 0; i < 4; ++i)
#pragma unroll
            for (int j = 0; j < 4; ++j) {
                int col = wid * 64 + j * 16 + ln;
                float bb = b1[col];
#pragma unroll
                for (int r = 0; r < 4; ++r) {
                    float v = acc[i][j][r] + bb;
                    v = v > 0.f ? v : 0.1f * v;
                    hdl[(i * 16 + q * 4 + r) * 264 + col] = f2bf(v);
                }
            }
    }
    __syncthreads();

    // stage 2: hd2 = lrelu(hd @ W2^T + b2)
    v4f acc2[4][4] = {};
    for (int kt = 0; kt < 8; ++kt) {
        v8s af[4], bf_[4];
#pragma unroll
        for (int i = 0; i < 4; ++i)
            af[i] = *(const v8s*)&hdl[(i * 16 + ln) * 264 + kt * 32 + q * 8];
#pragma unroll
        for (int j = 0; j < 4; ++j)
            bf_[j] = *(const v8s*)&w2[(size_t)(wid * 64 + j * 16 + ln) * 256 + kt * 32 + q * 8];
#pragma unroll
        for (int i = 0; i < 4; ++i)
#pragma unroll
            for (int j = 0; j < 4; ++j)
                acc2[i][j] = MFMA(af[i], bf_[j], acc2[i][j]);
    }
    __syncthreads();   // all stage-2 LDS reads done before overwrite
#pragma unroll
    for (int i = 0; i < 4; ++i)
#pragma unroll
        for (int j = 0; j < 4; ++j) {
            int col = wid * 64 + j * 16 + ln;
            float bb = b2[col];
#pragma unroll
            for (int r = 0; r < 4; ++r) {
                float v = acc2[i][j][r] + bb;
                v = v > 0.f ? v : 0.1f * v;
                hdl[(i * 16 + q * 4 + r) * 264 + col] = f2bf(v);
            }
        }
    __syncthreads();

    // stage 3: res = hd2 @ W3^T + b3; pred = P1 + res; emit out/pnew/xpad
    const int row = tid >> 2, seg = tid & 3;
    float s0 = 0.f, s1 = 0.f, s2 = 0.f;
#pragma unroll
    for (int t8 = 0; t8 < 8; ++t8) {
        v8s hv = *(const v8s*)&hdl[row * 264 + seg * 64 + t8 * 8];
#pragma unroll
        for (int e = 0; e < 8; ++e) {
            float f = bf2f((u16)hv[e]);
            int c = seg * 64 + t8 * 8 + e;
            s0 += f * w3l[c];
            s1 += f * w3l[256 + c];
            s2 += f * w3l[512 + c];
        }
    }
    s0 += __shfl_xor(s0, 1); s0 += __shfl_xor(s0, 2);
    s1 += __shfl_xor(s1, 1); s1 += __shfl_xor(s1, 2);
    s2 += __shfl_xor(s2, 1); s2 += __shfl_xor(s2, 2);
    if (seg == 0) {
        const int gm = r0 + row;
        float a0 = p1[gm * 3 + 0], a1 = p1[gm * 3 + 1], a2 = p1[gm * 3 + 2];
        float c0 = p2[gm * 3 + 0], c1 = p2[gm * 3 + 1], c2 = p2[gm * 3 + 2];
        float o0 = a0 + s0 + b3[0];
        float o1 = a1 + s1 + b3[1];
        float o2 = a2 + s2 + b3[2];
        size_t ob = ((size_t)gm * TS + s) * 3;
        out[ob + 0] = o0; out[ob + 1] = o1; out[ob + 2] = o2;
        pnew[gm * 3 + 0] = o0; pnew[gm * 3 + 1] = o1; pnew[gm * 3 + 2] = o2;
        u16 xs[32];
#pragma unroll
        for (int e = 0; e < 32; ++e) xs[e] = 0;
        xs[0] = f2bf(o0); xs[1] = f2bf(o1); xs[2] = f2bf(o2);
        xs[3] = f2bf(a0 - c0); xs[4] = f2bf(a1 - c1); xs[5] = f2bf(a2 - c2);
        xs[6] = f2bf(o0 - 2.f * a0 + c0);
        xs[7] = f2bf(o1 - 2.f * a1 + c1);
        xs[8] = f2bf(o2 - 2.f * a2 + c2);
        xs[9] = f2bf(1.f);
        uint4* xd = (uint4*)&xpad[(size_t)gm * 32];
#pragma unroll
        for (int t = 0; t < 4; ++t) {
            uint4 u;
            u.x = (unsigned)xs[t * 8 + 0] | ((unsigned)xs[t * 8 + 1] << 16);
            u.y = (unsigned)xs[t * 8 + 2] | ((unsigned)xs[t * 8 + 3] << 16);
            u.z = (unsigned)xs[t * 8 + 4] | ((unsigned)xs[t * 8 + 5] << 16);
            u.w = (unsigned)xs[t * 8 + 6] | ((unsigned)xs[t * 8 + 7] << 16);
            xd[t] = u;
        }
    }
}

// ---------------------------------------------------------------------------
// Step-0 xpad from the three input frames.
// ---------------------------------------------------------------------------
__global__ __launch_bounds__(256) void init_xpad(
    const float* __restrict__ x0, const float* __restrict__ xp,
    const float* __restrict__ xp2, u16* __restrict__ xpad)
{
    int m = blockIdx.x * 256 + threadIdx.x;
    float a0 = x0[m * 3 + 0], a1 = x0[m * 3 + 1], a2 = x0[m * 3 + 2];
    float b0 = xp[m * 3 + 0], b1 = xp[m * 3 + 1], b2 = xp[m * 3 + 2];
    float c0 = xp2[m * 3 + 0], c1 = xp2[m * 3 + 1], c2 = xp2[m * 3 + 2];
    unsigned t[32];
#pragma unroll
    for (int i = 0; i < 32; ++i) t[i] = 0;
    t[0] = f2bf(a0); t[1] = f2bf(a1); t[2] = f2bf(a2);
    t[3] = f2bf(b0 - c0); t[4] = f2bf(b1 - c1); t[5] = f2bf(b2 - c2);
    t[6] = f2bf(a0 - 2.f * b0 + c0);
    t[7] = f2bf(a1 - 2.f * b1 + c1);
    t[8] = f2bf(a2 - 2.f * b2 + c2);
    t[9] = f2bf(1.f);
    uint4* dst = (uint4*)&xpad[(size_t)m * 32];
#pragma unroll
    for (int wq = 0; wq < 4; ++wq) {
        uint4 u;
        u.x = t[wq * 8 + 0] | (t[wq * 8 + 1] << 16);
        u.y = t[wq * 8 + 2] | (t[wq * 8 + 3] << 16);
        u.z = t[wq * 8 + 4] | (t[wq * 8 + 5] << 16);
        u.w = t[wq * 8 + 6] | (t[wq * 8 + 7] << 16);
        dst[wq] = u;
    }
}

// ---------------------------------------------------------------------------
// hidden [N,C,V] fp32 -> h[(n,v),c] bf16.
// ---------------------------------------------------------------------------
__global__ __launch_bounds__(256) void transpose_h(
    const float* __restrict__ hidden, u16* __restrict__ hA)
{
    __shared__ float hl[256 * VN];
    const int n = blockIdx.x, tid = threadIdx.x;
    const uint4* src = (const uint4*)(hidden + (size_t)n * 256 * VN);
    for (int idx = tid; idx < 256 * VN / 4; idx += 256)
        ((uint4*)hl)[idx] = src[idx];
    __syncthreads();
    size_t base = (size_t)n * VN * 256;
    for (int idx = tid; idx < VN * 256; idx += 256) {
        int v = idx >> 8, c = idx & 255;
        hA[base + idx] = f2bf(hl[c * VN + v]);
    }
}

// ---------------------------------------------------------------------------
// fold_w: Wfold_g[j, k*256+c'] = sum_c Wh_g[j,c] * convw[k*256+c, c'] (bf16).
// One block per (g, kcp); 256 threads = j. convw factor is block-uniform.
// ---------------------------------------------------------------------------
__global__ __launch_bounds__(256) void fold_w(
    const float* __restrict__ Whr, const float* __restrict__ Whi,
    const float* __restrict__ Whh, const float* __restrict__ convw,
    u16* __restrict__ wfold)
{
    const int bid = blockIdx.x;            // 0..2303
    const int g = bid / 768, kcp = bid % 768;
    const int k = kcp >> 8, cp = kcp & 255;
    const float* Wg = g == 0 ? Whr : (g == 1 ? Whi : Whh);
    const int j = threadIdx.x;
    float acc = 0.f;
    for (int c = 0; c < 256; ++c)
        acc += Wg[j * 256 + c] * convw[(size_t)(k * 256 + c) * 256 + cp];
    wfold[(size_t)(g * 256 + j) * 800 + kcp] = f2bf(acc);
}

// ---------------------------------------------------------------------------
// gatebias_k: gb_g[w,j] = sum_c (sum_k convb[k*256+c]*S[k,w]) * Wh_g[j,c]
// with S[k,w] = sum_v aadj[k,v,w]. One block per (g,w); 256 threads = j.
// ---------------------------------------------------------------------------
__global__ __launch_bounds__(256) void gatebias_k(
    const float* __restrict__ Whr, const float* __restrict__ Whi,
    const float* __restrict__ Whh, const float* __restrict__ convb,
    const float* __restrict__ aadj, float* __restrict__ gbias)
{
    const int bid = blockIdx.x;            // 0..77
    const int g = bid / 26, w = bid % 26;
    const float* Wg = g == 0 ? Whr : (g == 1 ? Whi : Whh);
    float S[3];
#pragma unroll
    for (int k = 0; k < 3; ++k) {
        float sv = 0.f;
        for (int v = 0; v < VN; ++v) sv += aadj[(k * VN + v) * VN + w];
        S[k] = sv;
    }
    const int j = threadIdx.x;
    float acc = 0.f;
    for (int c = 0; c < 256; ++c) {
        float mb = convb[c] * S[0] + convb[256 + c] * S[1] + convb[512 + c] * S[2];
        acc += mb * Wg[j * 256 + c];
    }
    gbias[(size_t)(g * 26 + w) * 256 + j] = acc;
}

// ---------------------------------------------------------------------------
// Weight packing (once per call): wfull288, wfold x-cols, wxn, w1, w2, aadj.
// ---------------------------------------------------------------------------
__global__ __launch_bounds__(256) void pack_weights(
    const float* __restrict__ Whr, const float* __restrict__ Whi,
    const float* __restrict__ Whh, const float* __restrict__ W1f,
    const float* __restrict__ W2f, const float* __restrict__ Af,
    const float* __restrict__ emul, const float* __restrict__ eadd,
    const float* __restrict__ Wir, const float* __restrict__ Wii,
    const float* __restrict__ Win, const float* __restrict__ bir,
    const float* __restrict__ bii, const float* __restrict__ b_in,
    u16* __restrict__ wfull, u16* __restrict__ wfold, u16* __restrict__ wxn,
    u16* __restrict__ w1, u16* __restrict__ w2, float* __restrict__ aadj)
{
    int gid = blockIdx.x * 256 + threadIdx.x;
    int stride = gridDim.x * 256;
    // wfull288 [768 x 288]
    for (int i = gid; i < 768 * 288; i += stride) {
        int row = i / 288, col = i - row * 288;
        int g = row >> 8, c = row & 255;
        float v = 0.f;
        if (col < 256)
            v = (g == 0 ? Whr : (g == 1 ? Whi : Whh))[c * 256 + col];
        else if (col < 265) {
            int tcol = col - 256;
            v = (g == 0 ? Wir[c * 9 + tcol] : (g == 1 ? Wii[c * 9 + tcol] : 0.f));
        } else if (col == 265)
            v = (g == 0 ? bir[c] : (g == 1 ? bii[c] : 0.f));
        wfull[i] = f2bf(v);
    }
    // wfold x-cols [768 rows x cols 768..799]
    for (int i = gid; i < 768 * 32; i += stride) {
        int row = i >> 5, t = i & 31;
        int g = row >> 8, c = row & 255;
        float v = 0.f;
        if (t < 9) v = (g == 0 ? Wir[c * 9 + t] : (g == 1 ? Wii[c * 9 + t] : 0.f));
        else if (t == 9) v = (g == 0 ? bir[c] : (g == 1 ? bii[c] : 0.f));
        wfold[(size_t)row * 800 + 768 + t] = f2bf(v);
    }
    for (int i = gid; i < 256 * 32; i += stride) {
        int c = i >> 5, col = i & 31;
        float v = 0.f;
        if (col < 9) v = Win[c * 9 + col];
        else if (col == 9) v = b_in[c];
        wxn[i] = f2bf(v);
    }
    for (int i = gid; i < 65536; i += stride) {
        w1[i] = f2bf(W1f[i]);
        w2[i] = f2bf(W2f[i]);
    }
    for (int i = gid; i < KNUM * VN * VN; i += stride)
        aadj[i] = Af[i] * emul[i] + eadd[i];
}

// ---------------------------------------------------------------------------
extern "C" void kernel_launch(void* const* d_in, const int* in_sizes, int n_in,
                              void* d_out, int out_size, void* d_ws, size_t ws_size,
                              hipStream_t stream)
{
    const float* inputs   = (const float*)d_in[0];
    const float* inputs_p = (const float*)d_in[1];
    const float* inputs_p2= (const float*)d_in[2];
    const float* hidden   = (const float*)d_in[3];
    const float* Af       = (const float*)d_in[4];
    const float* emul     = (const float*)d_in[5];
    const float* eadd     = (const float*)d_in[6];
    const float* conv_w   = (const float*)d_in[7];
    const float* conv_b   = (const float*)d_in[8];
    const float* Wir      = (const float*)d_in[9];
    const float* bir      = (const float*)d_in[10];
    const float* Wii      = (const float*)d_in[11];
    const float* bii      = (const float*)d_in[12];
    const float* Win      = (const float*)d_in[13];
    const float* b_in     = (const float*)d_in[14];
    const float* Whr      = (const float*)d_in[15];
    const float* Whi      = (const float*)d_in[16];
    const float* Whh      = (const float*)d_in[17];
    const float* W1f      = (const float*)d_in[18];
    const float* b1f      = (const float*)d_in[19];
    const float* W2f      = (const float*)d_in[20];
    const float* b2f      = (const float*)d_in[21];
    const float* W3f      = (const float*)d_in[22];
    const float* b3f      = (const float*)d_in[23];
    float* out = (float*)d_out;

    const size_t M = M_ROWS;
    char* ws = (char*)d_ws;
    size_t off = 0;
    auto alloc = [&](size_t bytes) -> void* {
        void* p = ws + off;
        off = (off + bytes + 255) & ~(size_t)255;
        return p;
    };
    u16* z     = (u16*)alloc(M * 768 * 2);
    u16* hA    = (u16*)alloc(M * 256 * 2);
    u16* hB    = (u16*)alloc(M * 256 * 2);
    u16* xpad  = (u16*)alloc(M * 32 * 2);
    float* pa  = (float*)alloc(M * 3 * 4);
    float* pb  = (float*)alloc(M * 3 * 4);
    float* pc  = (float*)alloc(M * 3 * 4);
    u16* wfull = (u16*)alloc(768 * 288 * 2);
    u16* wfold = (u16*)alloc(768 * 800 * 2);
    u16* wxn   = (u16*)alloc(256 * 32 * 2);
    u16* w1    = (u16*)alloc(65536 * 2);
    u16* w2    = (u16*)alloc(65536 * 2);
    float* aadj  = (float*)alloc(KNUM * VN * VN * 4);
    float* gbias = (float*)alloc(3 * 26 * 256 * 4);
    if (off > ws_size) return;

    pack_weights<<<512, 256, 0, stream>>>(
        Whr, Whi, Whh, W1f, W2f, Af, emul, eadd, Wir, Wii, Win,
        bir, bii, b_in, wfull, wfold, wxn, w1, w2, aadj);
    fold_w<<<2304, 256, 0, stream>>>(Whr, Whi, Whh, conv_w, wfold);
    gatebias_k<<<78, 256, 0, stream>>>(Whr, Whi, Whh, conv_b, aadj, gbias);
    transpose_h<<<NBATCH, 256, 0, stream>>>(hidden, hA);
    init_xpad<<<M_ROWS / 256, 256, 0, stream>>>(inputs, inputs_p, inputs_p2, xpad);
    hipMemcpyAsync(pa, inputs,    M * 3 * 4, hipMemcpyDeviceToDevice, stream);
    hipMemcpyAsync(pb, inputs_p,  M * 3 * 4, hipMemcpyDeviceToDevice, stream);
    hipMemcpyAsync(pc, inputs_p2, M * 3 * 4, hipMemcpyDeviceToDevice, stream);

    u16* hcur = hA;  u16* hnext = hB;
    float* P1 = pa;  float* P2 = pb;  float* P3 = pc;

    for (int s = 0; s < TS; ++s) {
        if (s < 10) {
            mix3<<<NBATCH, 256, 0, stream>>>(hcur, aadj, z);
            gru_direct<25, 768, 800, 1><<<3328, 256, 0, stream>>>(
                z, xpad, hcur, hnext, wfold, wxn, gbias);
        } else {
            gru_direct<9, 256, 288, 0><<<3328, 256, 0, stream>>>(
                hcur, xpad, hcur, hnext, wfull, wxn, nullptr);
        }
        mlp_head<<<M_ROWS / 64, 256, 0, stream>>>(
            hnext, w1, b1f, w2, b2f, W3f, b3f, P1, P2, P3, xpad, out, s);
        float* t = P3; P3 = P2; P2 = P1; P1 = t;
        u16* ht = hcur; hcur = hnext; hnext = ht;
    }
}

// Round 4
// 8256.107 us; speedup vs baseline: 1.2682x; 1.2682x over previous
//
#include <hip/hip_runtime.h>

// Problem constants (fixed by the reference)
#define M_ROWS 106496   // 4096*26  (n,v) rows
#define NBATCH 4096
#define VN 26
#define KNUM 3
#define TS 25

typedef unsigned short u16;
typedef __attribute__((ext_vector_type(8))) short v8s;
typedef __attribute__((ext_vector_type(4))) float v4f;

#define MFMA(a, b, c) __builtin_amdgcn_mfma_f32_16x16x32_bf16(a, b, c, 0, 0, 0)

__device__ __forceinline__ u16 f2bf(float f) {
    unsigned u = __float_as_uint(f);
    u += 0x7FFF + ((u >> 16) & 1);   // RNE
    return (u16)(u >> 16);
}
__device__ __forceinline__ float bf2f(u16 h) {
    return __uint_as_float(((unsigned)h) << 16);
}
__device__ __forceinline__ float sigm(float x) {
    return 1.f / (1.f + __expf(-x));
}
__device__ __forceinline__ float tanh_fast(float x) {
    return 2.f / (1.f + __expf(-2.f * x)) - 1.f;
}

// Async global->LDS, 16B/lane. LDS dest = wave-uniform base; HW adds lane*16.
// Global source address may vary per lane.
typedef const __attribute__((address_space(1))) unsigned int* gas_t;
typedef __attribute__((address_space(3))) unsigned int* las_t;
__device__ __forceinline__ void gl16(const void* g, void* l) {
    __builtin_amdgcn_global_load_lds((gas_t)g, (las_t)l, 16, 0, 0);
}

// ---------------------------------------------------------------------------
// GRU with B pinned in LDS (r,z gates, K-tiles 0..7 = 64 KB exactly) and a
// barrier-free K-loop: A fragments global->reg (L3-resident activations),
// h-gate B + last (xpad) tile B direct from L2. One __syncthreads total.
// K=288: cols 0..255 = msg/h @ Wh*, cols 256..287 = xpad (x-proj + bias).
// Block 256 thr = 4 waves (2x2), tile 128m x 64n x 3 gates. Grid (832,4).
// ---------------------------------------------------------------------------
__global__ __launch_bounds__(256) void gru_bpin(
    const u16* __restrict__ Am, const u16* __restrict__ xpad,
    const u16* __restrict__ hprev, u16* __restrict__ hout,
    const u16* __restrict__ wfull, const u16* __restrict__ wxn)
{
    __shared__ u16 Bl[8 * 128 * 32];   // 64 KB
    const int m0 = blockIdx.x * 128;
    const int n0 = blockIdx.y * 64;
    const int tid = threadIdx.x, wid = tid >> 6, lane = tid & 63;
    const int ln = lane & 15, q = lane >> 4;
    const int wm = (wid >> 1) * 64, wn = (wid & 1) * 32;

    // prologue: pin r,z-gate B tiles. Bl[kt][row(g*64+rl)][32cols].
    {
        const int lrow = lane >> 2, lc = lane & 3;
#pragma unroll
        for (int p = 0; p < 16; ++p) {
            int u = p * 4 + wid;                 // 0..63, unique (kt,rg)
            int kt = u >> 3, rg = (u & 7) * 16;
            int gr = rg + lrow;                  // 0..127
            int wrow = (gr >> 6) * 256 + n0 + (gr & 63);
            gl16(&wfull[(size_t)wrow * 288 + kt * 32 + lc * 8],
                 &Bl[(kt * 128 + rg) * 32]);
        }
    }
    __syncthreads();   // single barrier; Bl is read-only afterwards

    const u16* Arow[4];
#pragma unroll
    for (int i = 0; i < 4; ++i)
        Arow[i] = Am + (size_t)(m0 + wm + i * 16 + ln) * 256 + q * 8;
    const u16* Bh[2];
#pragma unroll
    for (int j = 0; j < 2; ++j)
        Bh[j] = wfull + (size_t)(512 + n0 + wn + j * 16 + ln) * 288 + q * 8;

    v4f accr[4][2] = {}, accz[4][2] = {}, acch[4][2] = {}, accn[4][2] = {};

#pragma unroll
    for (int kt = 0; kt < 8; ++kt) {
        v8s af[4], br[2], bz[2], bh[2];
#pragma unroll
        for (int i = 0; i < 4; ++i) af[i] = *(const v8s*)(Arow[i] + kt * 32);
#pragma unroll
        for (int j = 0; j < 2; ++j) {
            int rl = wn + j * 16 + ln;
            br[j] = *(const v8s*)&Bl[(kt * 128 + rl) * 32 + q * 8];
            bz[j] = *(const v8s*)&Bl[(kt * 128 + 64 + rl) * 32 + q * 8];
            bh[j] = *(const v8s*)(Bh[j] + kt * 32);
        }
#pragma unroll
        for (int i = 0; i < 4; ++i)
#pragma unroll
            for (int j = 0; j < 2; ++j) {
                accr[i][j] = MFMA(af[i], br[j], accr[i][j]);
                accz[i][j] = MFMA(af[i], bz[j], accz[i][j]);
                acch[i][j] = MFMA(af[i], bh[j], acch[i][j]);
            }
    }
    // last tile: A = xpad, B = wfull cols 256..287 (direct), + wxn (n-gate x)
    {
        v8s af[4], br[2], bz[2], bh[2], bn[2];
#pragma unroll
        for (int i = 0; i < 4; ++i)
            af[i] = *(const v8s*)&xpad[(size_t)(m0 + wm + i * 16 + ln) * 32 + q * 8];
#pragma unroll
        for (int j = 0; j < 2; ++j) {
            int rl = n0 + wn + j * 16 + ln;
            br[j] = *(const v8s*)&wfull[(size_t)rl * 288 + 256 + q * 8];
            bz[j] = *(const v8s*)&wfull[(size_t)(256 + rl) * 288 + 256 + q * 8];
            bh[j] = *(const v8s*)(Bh[j] + 256);
            bn[j] = *(const v8s*)&wxn[(size_t)(n0 + wn + j * 16 + ln) * 32 + q * 8];
        }
#pragma unroll
        for (int i = 0; i < 4; ++i)
#pragma unroll
            for (int j = 0; j < 2; ++j) {
                accr[i][j] = MFMA(af[i], br[j], accr[i][j]);
                accz[i][j] = MFMA(af[i], bz[j], accz[i][j]);
                acch[i][j] = MFMA(af[i], bh[j], acch[i][j]);
                accn[i][j] = MFMA(af[i], bn[j], accn[i][j]);
            }
    }

#pragma unroll
    for (int i = 0; i < 4; ++i)
#pragma unroll
        for (int j = 0; j < 2; ++j) {
            int gc = n0 + wn + j * 16 + ln;
#pragma unroll
            for (int r = 0; r < 4; ++r) {
                int gr = m0 + wm + i * 16 + q * 4 + r;
                float rg = sigm(accr[i][j][r]);
                float zg = sigm(accz[i][j][r]);
                float nn = tanh_fast(accn[i][j][r] + rg * acch[i][j][r]);
                float hp = bf2f(hprev[(size_t)gr * 256 + gc]);
                hout[(size_t)gr * 256 + gc] = f2bf((1.f - zg) * nn + zg * hp);
            }
        }
}

// ---------------------------------------------------------------------------
// Conv gemm with B pinned in LDS (128-col slice of convw = 64 KB), barrier-
// free K-loop. y[(n,v), o] = h[(n,v),:] @ convw[o,:] + conv_b[o], o in 0..767.
// Block 256 thr = 4 waves (2x2, wave 64x64), grid (832, 6).
// ---------------------------------------------------------------------------
__global__ __launch_bounds__(256) void conv_bpin(
    const u16* __restrict__ A, const u16* __restrict__ convw,
    const float* __restrict__ convb, u16* __restrict__ y)
{
    __shared__ u16 Bl[8 * 128 * 32];   // 64 KB
    const int m0 = blockIdx.x * 128;
    const int n0 = blockIdx.y * 128;
    const int tid = threadIdx.x, wid = tid >> 6, lane = tid & 63;
    const int ln = lane & 15, q = lane >> 4;
    const int wm = (wid >> 1) * 64, wn = (wid & 1) * 64;

    {
        const int lrow = lane >> 2, lc = lane & 3;
#pragma unroll
        for (int p = 0; p < 16; ++p) {
            int u = p * 4 + wid;
            int kt = u >> 3, rg = (u & 7) * 16;
            int gr = rg + lrow;
            gl16(&convw[(size_t)(n0 + gr) * 256 + kt * 32 + lc * 8],
                 &Bl[(kt * 128 + rg) * 32]);
        }
    }
    __syncthreads();

    const u16* Arow[4];
#pragma unroll
    for (int i = 0; i < 4; ++i)
        Arow[i] = A + (size_t)(m0 + wm + i * 16 + ln) * 256 + q * 8;

    v4f acc[4][4] = {};
#pragma unroll
    for (int kt = 0; kt < 8; ++kt) {
        v8s af[4], bf_[4];
#pragma unroll
        for (int i = 0; i < 4; ++i) af[i] = *(const v8s*)(Arow[i] + kt * 32);
#pragma unroll
        for (int j = 0; j < 4; ++j)
            bf_[j] = *(const v8s*)&Bl[(kt * 128 + wn + j * 16 + ln) * 32 + q * 8];
#pragma unroll
        for (int i = 0; i < 4; ++i)
#pragma unroll
            for (int j = 0; j < 4; ++j)
                acc[i][j] = MFMA(af[i], bf_[j], acc[i][j]);
    }
#pragma unroll
    for (int i = 0; i < 4; ++i)
#pragma unroll
        for (int j = 0; j < 4; ++j) {
            int gc = n0 + wn + j * 16 + ln;
            float b = convb[gc];
#pragma unroll
            for (int r = 0; r < 4; ++r) {
                int gr = m0 + wm + i * 16 + q * 4 + r;
                y[(size_t)gr * 768 + gc] = f2bf(acc[i][j][r] + b);
            }
        }
}

// ---------------------------------------------------------------------------
// Graph mix: msg[(n,w),c] = sum_{k,v} y[(n,v),k*256+c] * aadj[k][v][w]
// ---------------------------------------------------------------------------
__global__ __launch_bounds__(256) void graph_mix(
    const u16* __restrict__ y, const float* __restrict__ aadj,
    u16* __restrict__ msg)
{
    __shared__ u16 yl[VN * 768];
    const int n = blockIdx.x, tid = threadIdx.x;
    const uint4* src = (const uint4*)(y + (size_t)n * VN * 768);
    for (int idx = tid; idx < VN * 768 / 8; idx += 256)
        ((uint4*)yl)[idx] = src[idx];
    __syncthreads();
    const int c = tid;
    float acc[VN] = {};
    for (int k = 0; k < KNUM; ++k)
        for (int v = 0; v < VN; ++v) {
            float yv = bf2f(yl[v * 768 + k * 256 + c]);
            const float* ap = &aadj[(k * VN + v) * VN];
#pragma unroll
            for (int w = 0; w < VN; ++w) acc[w] += yv * ap[w];
        }
    size_t base = (size_t)n * VN * 256;
    for (int w = 0; w < VN; ++w) msg[base + w * 256 + c] = f2bf(acc[w]);
}

// ---------------------------------------------------------------------------
// Fused MLP + head (validated in R3): hd=lrelu(h@W1^T+b1); hd2=lrelu(hd@W2^T
// +b2); res=hd2@W3^T+b3; pred=P1+res -> out[:,s], pnew, next xpad.
// hd/hd2 live only in LDS. W1/W2 direct from global (L2-resident).
// ---------------------------------------------------------------------------
__global__ __launch_bounds__(256) void mlp_head(
    const u16* __restrict__ h, const u16* __restrict__ w1,
    const float* __restrict__ b1, const u16* __restrict__ w2,
    const float* __restrict__ b2, const float* __restrict__ w3,
    const float* __restrict__ b3, const float* __restrict__ p1,
    const float* __restrict__ p2, float* __restrict__ pnew,
    u16* __restrict__ xpad, float* __restrict__ out, int s)
{
    __shared__ u16 hdl[64 * 264];
    __shared__ float w3l[768];
    const int tid = threadIdx.x, wid = tid >> 6, lane = tid & 63;
    const int ln = lane & 15, q = lane >> 4;
    const int r0 = blockIdx.x * 64;
    for (int idx = tid; idx < 768; idx += 256) w3l[idx] = w3[idx];

    // stage 1: hd = lrelu(h @ W1^T + b1)
    {
        v4f acc[4][4] = {};
#pragma unroll
        for (int kt = 0; kt < 8; ++kt) {
            v8s af[4], bf_[4];
#pragma unroll
            for (int i = 0; i < 4; ++i)
                af[i] = *(const v8s*)&h[(size_t)(r0 + i * 16 + ln) * 256 + kt * 32 + q * 8];
#pragma unroll
            for (int j = 0; j < 4; ++j)
                bf_[j] = *(const v8s*)&w1[(size_t)(wid * 64 + j * 16 + ln) * 256 + kt * 32 + q * 8];
#pragma unroll
            for (int i = 0; i < 4; ++i)
#pragma unroll
                for (int j = 0; j < 4; ++j)
                    acc[i][j] = MFMA(af[i], bf_[j], acc[i][j]);
        }
#pragma unroll
        for (int i = 0; i < 4; ++i)
#pragma unroll
            for (int j = 0; j < 4; ++j) {
                int col = wid * 64 + j * 16 + ln;
                float bb = b1[col];
#pragma unroll
                for (int r = 0; r < 4; ++r) {
                    float v = acc[i][j][r] + bb;
                    v = v > 0.f ? v : 0.1f * v;
                    hdl[(i * 16 + q * 4 + r) * 264 + col] = f2bf(v);
                }
            }
    }
    __syncthreads();

    // stage 2: hd2 = lrelu(hd @ W2^T + b2)
    v4f acc2[4][4] = {};
#pragma unroll
    for (int kt = 0; kt < 8; ++kt) {
        v8s af[4], bf_[4];
#pragma unroll
        for (int i = 0; i < 4; ++i)
            af[i] = *(const v8s*)&hdl[(i * 16 + ln) * 264 + kt * 32 + q * 8];
#pragma unroll
        for (int j = 0; j < 4; ++j)
            bf_[j] = *(const v8s*)&w2[(size_t)(wid * 64 + j * 16 + ln) * 256 + kt * 32 + q * 8];
#pragma unroll
        for (int i = 0; i < 4; ++i)
#pragma unroll
            for (int j = 0; j < 4; ++j)
                acc2[i][j] = MFMA(af[i], bf_[j], acc2[i][j]);
    }
    __syncthreads();
#pragma unroll
    for (int i = 0; i < 4; ++i)
#pragma unroll
        for (int j = 0; j < 4; ++j) {
            int col = wid * 64 + j * 16 + ln;
            float bb = b2[col];
#pragma unroll
            for (int r = 0; r < 4; ++r) {
                float v = acc2[i][j][r] + bb;
                v = v > 0.f ? v : 0.1f * v;
                hdl[(i * 16 + q * 4 + r) * 264 + col] = f2bf(v);
            }
        }
    __syncthreads();

    // stage 3: res = hd2 @ W3^T + b3; pred = P1 + res
    const int row = tid >> 2, seg = tid & 3;
    float s0 = 0.f, s1 = 0.f, s2 = 0.f;
#pragma unroll
    for (int t8 = 0; t8 < 8; ++t8) {
        v8s hv = *(const v8s*)&hdl[row * 264 + seg * 64 + t8 * 8];
#pragma unroll
        for (int e = 0; e < 8; ++e) {
            float f = bf2f((u16)hv[e]);
            int c = seg * 64 + t8 * 8 + e;
            s0 += f * w3l[c];
            s1 += f * w3l[256 + c];
            s2 += f * w3l[512 + c];
        }
    }
    s0 += __shfl_xor(s0, 1); s0 += __shfl_xor(s0, 2);
    s1 += __shfl_xor(s1, 1); s1 += __shfl_xor(s1, 2);
    s2 += __shfl_xor(s2, 1); s2 += __shfl_xor(s2, 2);
    if (seg == 0) {
        const int gm = r0 + row;
        float a0 = p1[gm * 3 + 0], a1 = p1[gm * 3 + 1], a2 = p1[gm * 3 + 2];
        float c0 = p2[gm * 3 + 0], c1 = p2[gm * 3 + 1], c2 = p2[gm * 3 + 2];
        float o0 = a0 + s0 + b3[0];
        float o1 = a1 + s1 + b3[1];
        float o2 = a2 + s2 + b3[2];
        size_t ob = ((size_t)gm * TS + s) * 3;
        out[ob + 0] = o0; out[ob + 1] = o1; out[ob + 2] = o2;
        pnew[gm * 3 + 0] = o0; pnew[gm * 3 + 1] = o1; pnew[gm * 3 + 2] = o2;
        u16 xs[32];
#pragma unroll
        for (int e = 0; e < 32; ++e) xs[e] = 0;
        xs[0] = f2bf(o0); xs[1] = f2bf(o1); xs[2] = f2bf(o2);
        xs[3] = f2bf(a0 - c0); xs[4] = f2bf(a1 - c1); xs[5] = f2bf(a2 - c2);
        xs[6] = f2bf(o0 - 2.f * a0 + c0);
        xs[7] = f2bf(o1 - 2.f * a1 + c1);
        xs[8] = f2bf(o2 - 2.f * a2 + c2);
        xs[9] = f2bf(1.f);
        uint4* xd = (uint4*)&xpad[(size_t)gm * 32];
#pragma unroll
        for (int t = 0; t < 4; ++t) {
            uint4 u;
            u.x = (unsigned)xs[t * 8 + 0] | ((unsigned)xs[t * 8 + 1] << 16);
            u.y = (unsigned)xs[t * 8 + 2] | ((unsigned)xs[t * 8 + 3] << 16);
            u.z = (unsigned)xs[t * 8 + 4] | ((unsigned)xs[t * 8 + 5] << 16);
            u.w = (unsigned)xs[t * 8 + 6] | ((unsigned)xs[t * 8 + 7] << 16);
            xd[t] = u;
        }
    }
}

// ---------------------------------------------------------------------------
// Step-0 xpad from the three input frames.
// ---------------------------------------------------------------------------
__global__ __launch_bounds__(256) void init_xpad(
    const float* __restrict__ x0, const float* __restrict__ xp,
    const float* __restrict__ xp2, u16* __restrict__ xpad)
{
    int m = blockIdx.x * 256 + threadIdx.x;
    float a0 = x0[m * 3 + 0], a1 = x0[m * 3 + 1], a2 = x0[m * 3 + 2];
    float b0 = xp[m * 3 + 0], b1 = xp[m * 3 + 1], b2 = xp[m * 3 + 2];
    float c0 = xp2[m * 3 + 0], c1 = xp2[m * 3 + 1], c2 = xp2[m * 3 + 2];
    unsigned t[32];
#pragma unroll
    for (int i = 0; i < 32; ++i) t[i] = 0;
    t[0] = f2bf(a0); t[1] = f2bf(a1); t[2] = f2bf(a2);
    t[3] = f2bf(b0 - c0); t[4] = f2bf(b1 - c1); t[5] = f2bf(b2 - c2);
    t[6] = f2bf(a0 - 2.f * b0 + c0);
    t[7] = f2bf(a1 - 2.f * b1 + c1);
    t[8] = f2bf(a2 - 2.f * b2 + c2);
    t[9] = f2bf(1.f);
    uint4* dst = (uint4*)&xpad[(size_t)m * 32];
#pragma unroll
    for (int wq = 0; wq < 4; ++wq) {
        uint4 u;
        u.x = t[wq * 8 + 0] | (t[wq * 8 + 1] << 16);
        u.y = t[wq * 8 + 2] | (t[wq * 8 + 3] << 16);
        u.z = t[wq * 8 + 4] | (t[wq * 8 + 5] << 16);
        u.w = t[wq * 8 + 6] | (t[wq * 8 + 7] << 16);
        dst[wq] = u;
    }
}

// ---------------------------------------------------------------------------
// hidden [N,C,V] fp32 -> h[(n,v),c] bf16.
// ---------------------------------------------------------------------------
__global__ __launch_bounds__(256) void transpose_h(
    const float* __restrict__ hidden, u16* __restrict__ hA)
{
    __shared__ float hl[256 * VN];
    const int n = blockIdx.x, tid = threadIdx.x;
    const uint4* src = (const uint4*)(hidden + (size_t)n * 256 * VN);
    for (int idx = tid; idx < 256 * VN / 4; idx += 256)
        ((uint4*)hl)[idx] = src[idx];
    __syncthreads();
    size_t base = (size_t)n * VN * 256;
    for (int idx = tid; idx < VN * 256; idx += 256) {
        int v = idx >> 8, c = idx & 255;
        hA[base + idx] = f2bf(hl[c * VN + v]);
    }
}

// ---------------------------------------------------------------------------
// Weight packing (once per call): wfull288, wxn, w1, w2, convw, aadj.
// ---------------------------------------------------------------------------
__global__ __launch_bounds__(256) void pack_weights(
    const float* __restrict__ Whr, const float* __restrict__ Whi,
    const float* __restrict__ Whh, const float* __restrict__ W1f,
    const float* __restrict__ W2f, const float* __restrict__ convw_f,
    const float* __restrict__ Af, const float* __restrict__ emul,
    const float* __restrict__ eadd, const float* __restrict__ Wir,
    const float* __restrict__ Wii, const float* __restrict__ Win,
    const float* __restrict__ bir, const float* __restrict__ bii,
    const float* __restrict__ b_in,
    u16* __restrict__ wfull, u16* __restrict__ wxn, u16* __restrict__ w1,
    u16* __restrict__ w2, u16* __restrict__ convw, float* __restrict__ aadj)
{
    int gid = blockIdx.x * 256 + threadIdx.x;
    int stride = gridDim.x * 256;
    for (int i = gid; i < 768 * 288; i += stride) {
        int row = i / 288, col = i - row * 288;
        int g = row >> 8, c = row & 255;
        float v = 0.f;
        if (col < 256)
            v = (g == 0 ? Whr : (g == 1 ? Whi : Whh))[c * 256 + col];
        else if (col < 265) {
            int tcol = col - 256;
            v = (g == 0 ? Wir[c * 9 + tcol] : (g == 1 ? Wii[c * 9 + tcol] : 0.f));
        } else if (col == 265)
            v = (g == 0 ? bir[c] : (g == 1 ? bii[c] : 0.f));
        wfull[i] = f2bf(v);
    }
    for (int i = gid; i < 256 * 32; i += stride) {
        int c = i >> 5, col = i & 31;
        float v = 0.f;
        if (col < 9) v = Win[c * 9 + col];
        else if (col == 9) v = b_in[c];
        wxn[i] = f2bf(v);
    }
    for (int i = gid; i < 65536; i += stride) {
        w1[i] = f2bf(W1f[i]);
        w2[i] = f2bf(W2f[i]);
    }
    for (int i = gid; i < 196608; i += stride) convw[i] = f2bf(convw_f[i]);
    for (int i = gid; i < KNUM * VN * VN; i += stride)
        aadj[i] = Af[i] * emul[i] + eadd[i];
}

// ---------------------------------------------------------------------------
extern "C" void kernel_launch(void* const* d_in, const int* in_sizes, int n_in,
                              void* d_out, int out_size, void* d_ws, size_t ws_size,
                              hipStream_t stream)
{
    const float* inputs   = (const float*)d_in[0];
    const float* inputs_p = (const float*)d_in[1];
    const float* inputs_p2= (const float*)d_in[2];
    const float* hidden   = (const float*)d_in[3];
    const float* Af       = (const float*)d_in[4];
    const float* emul     = (const float*)d_in[5];
    const float* eadd     = (const float*)d_in[6];
    const float* conv_w   = (const float*)d_in[7];
    const float* conv_b   = (const float*)d_in[8];
    const float* Wir      = (const float*)d_in[9];
    const float* bir      = (const float*)d_in[10];
    const float* Wii      = (const float*)d_in[11];
    const float* bii      = (const float*)d_in[12];
    const float* Win      = (const float*)d_in[13];
    const float* b_in     = (const float*)d_in[14];
    const float* Whr      = (const float*)d_in[15];
    const float* Whi      = (const float*)d_in[16];
    const float* Whh      = (const float*)d_in[17];
    const float* W1f      = (const float*)d_in[18];
    const float* b1f      = (const float*)d_in[19];
    const float* W2f      = (const float*)d_in[20];
    const float* b2f      = (const float*)d_in[21];
    const float* W3f      = (const float*)d_in[22];
    const float* b3f      = (const float*)d_in[23];
    float* out = (float*)d_out;

    const size_t M = M_ROWS;
    char* ws = (char*)d_ws;
    size_t off = 0;
    auto alloc = [&](size_t bytes) -> void* {
        void* p = ws + off;
        off = (off + bytes + 255) & ~(size_t)255;
        return p;
    };
    u16* ybuf  = (u16*)alloc(M * 768 * 2);
    u16* msg   = (u16*)alloc(M * 256 * 2);
    u16* hA    = (u16*)alloc(M * 256 * 2);
    u16* hB    = (u16*)alloc(M * 256 * 2);
    u16* xpad  = (u16*)alloc(M * 32 * 2);
    float* pa  = (float*)alloc(M * 3 * 4);
    float* pb  = (float*)alloc(M * 3 * 4);
    float* pc  = (float*)alloc(M * 3 * 4);
    u16* wfull = (u16*)alloc(768 * 288 * 2);
    u16* wxn   = (u16*)alloc(256 * 32 * 2);
    u16* w1    = (u16*)alloc(65536 * 2);
    u16* w2    = (u16*)alloc(65536 * 2);
    u16* convw = (u16*)alloc(196608 * 2);
    float* aadj = (float*)alloc(KNUM * VN * VN * 4);
    if (off > ws_size) return;

    pack_weights<<<512, 256, 0, stream>>>(
        Whr, Whi, Whh, W1f, W2f, conv_w, Af, emul, eadd, Wir, Wii, Win,
        bir, bii, b_in, wfull, wxn, w1, w2, convw, aadj);
    transpose_h<<<NBATCH, 256, 0, stream>>>(hidden, hA);
    init_xpad<<<M_ROWS / 256, 256, 0, stream>>>(inputs, inputs_p, inputs_p2, xpad);
    hipMemcpyAsync(pa, inputs,    M * 3 * 4, hipMemcpyDeviceToDevice, stream);
    hipMemcpyAsync(pb, inputs_p,  M * 3 * 4, hipMemcpyDeviceToDevice, stream);
    hipMemcpyAsync(pc, inputs_p2, M * 3 * 4, hipMemcpyDeviceToDevice, stream);

    u16* hcur = hA;  u16* hnext = hB;
    float* P1 = pa;  float* P2 = pb;  float* P3 = pc;
    const int MB = M_ROWS / 128;  // 832

    for (int s = 0; s < TS; ++s) {
        const u16* m_ptr;
        if (s < 10) {
            conv_bpin<<<dim3(MB, 6), 256, 0, stream>>>(hcur, convw, conv_b, ybuf);
            graph_mix<<<NBATCH, 256, 0, stream>>>(ybuf, aadj, msg);
            m_ptr = msg;
        } else {
            m_ptr = hcur;
        }
        gru_bpin<<<dim3(MB, 4), 256, 0, stream>>>(m_ptr, xpad, hcur, hnext,
                                                  wfull, wxn);
        mlp_head<<<M_ROWS / 64, 256, 0, stream>>>(
            hnext, w1, b1f, w2, b2f, W3f, b3f, P1, P2, P3, xpad, out, s);
        float* t = P3; P3 = P2; P2 = P1; P1 = t;
        u16* ht = hcur; hcur = hnext; hnext = ht;
    }
}